// Round 15
// baseline (331.295 us; speedup 1.0000x reference)
//
#include <hip/hip_runtime.h>
#include <hip/hip_bf16.h>

// GeneratorSDF: latent-conditioned MLP SDF on a 128^3 grid (fp32 I/O).
// dims: 67 -> 128 -> 64 -> 32 -> 1 (relu, relu, relu, sigmoid)
//
// R15: RESIDENCY theory. Occupancy has tracked (VGPR_Count + 64 AGPR for a2)
// all session: ~180 total regs -> 2 waves/SIMD (18-21% occ, R4-R14), and R7's
// accidental VGPR=64 spill-fest hit 45% occ. Four neutral issue-reduction
// rounds (R9/R12/R13/R14) mean we're latency-bound at residency 2.
// Changes: __launch_bounds__(256,3) (target 512/3=170 total regs: ~10-reg
// trim, NOT R7's 64-cap), drop R13's neutral reg-pins, grid 2048 (1024
// pts/block, 16 ng) so 8 blocks/CU pipeline through 3-resident slots.
// Keeps: cheap 3-instr pk2 (R14), pipelined h2 double-buffer + b3f prefetch
// (R8/R12), batched cphase, LDS union, LDS-table h1 build (R12 style —
// R13 proved table DS reads are free).
// MFMA layouts (verified m89/m91): A[m=lane&15][k=quad*8+j],
// B[k=quad*8+j][n=lane&15], C/D row=quad*4+reg, col=lane&15.

#define NPTS (128 * 128 * 128)

typedef float f32x4_t __attribute__((ext_vector_type(4)));
typedef float f32x2_t __attribute__((ext_vector_type(2)));
typedef short bf16x8_t __attribute__((ext_vector_type(8)));

// f32x2 -> packed bf16x2, round-half-up: 2x v_add_u32 + 1x v_perm_b32.
__device__ __forceinline__ unsigned pk2(float lo, float hi) {
    unsigned a, b;
    __builtin_memcpy(&a, &lo, 4);
    __builtin_memcpy(&b, &hi, 4);
    return __builtin_amdgcn_perm(b + 0x8000u, a + 0x8000u, 0x07060302u);
}

__global__ __launch_bounds__(256, 3) void mlp_kernel(
    const float* __restrict__ x,  const float* __restrict__ W1,
    const float* __restrict__ b1, const float* __restrict__ W2,
    const float* __restrict__ b2, const float* __restrict__ W3,
    const float* __restrict__ b3, const float* __restrict__ W4,
    const float* __restrict__ b4, float* __restrict__ out) {
    __shared__ __align__(16) float s_base[8][128];   // j-row: base+wa*pa+wb*pb_j
    __shared__ __align__(16) float s_wc[128];        // wc[k]
    __shared__ __align__(16) float s_b2[64];
    __shared__ __align__(16) float s_b3[32];
    __shared__ __align__(16) float s_w4[32];
    // Union (26.6 KB): staging = w2a[16][64][8] (shorts 0..8191) + w3a[4][64][8]
    // (8192..10239); runtime = h2 slots [w][2][16][72] (0..9215) + z floats
    // (shorts 9216..13311 = float[4][8][16][4] : w*512 + pg*64 + i*4 + q).
    __shared__ __align__(16) unsigned short s_u[13312];

    const int t = threadIdx.x;
    const int w = t >> 6;
    const int lane = t & 63;
    const int quad = lane >> 4;
    const int l15 = lane & 15;
    const float step = 2.0f / 127.0f;

    // ================= per-block prep =================
    if (t < 128) {
        const float* w1row = W1 + t * 67;
        float s = b1[t];
#pragma unroll 8
        for (int c = 0; c < 64; ++c) s = fmaf(w1row[c], x[c], s);
        const float wa = w1row[64], wb = w1row[65], wc = w1row[66];
        const float pa = -1.0f + step * (float)(blockIdx.x >> 4);   // gi
        const float base = fmaf(wa, pa, s);
        const int gj0 = (blockIdx.x & 15) * 8;
        s_wc[t] = wc;
#pragma unroll
        for (int j = 0; j < 8; ++j) {
            const float pb = -1.0f + step * (float)(gj0 + j);
            s_base[j][t] = fmaf(wb, pb, base);
        }
    }
    // W2 [64][128] -> bf16 A-frag staging
    const float2* W2v = (const float2*)W2;
#pragma unroll
    for (int it = 0; it < 16; ++it) {
        int pidx = t + 256 * it;
        int idx2 = pidx * 2;
        int o = idx2 >> 7, k = idx2 & 127;
        int mt = o >> 4, lm = o & 15;
        int kb = k >> 5, q = (k >> 3) & 3, jj = k & 7;
        float2 v = W2v[pidx];
        *(unsigned*)&s_u[(mt * 4 + kb) * 512 + (q * 16 + lm) * 8 + jj] = pk2(v.x, v.y);
    }
    // W3 [32][64] -> bf16 A-frag staging
    const float2* W3v = (const float2*)W3;
#pragma unroll
    for (int it = 0; it < 4; ++it) {
        int pidx = t + 256 * it;
        int idx2 = pidx * 2;
        int o = idx2 >> 6, k = idx2 & 63;
        int mt = o >> 4, lm = o & 15;
        int kb = k >> 5, q = (k >> 3) & 3, jj = k & 7;
        float2 v = W3v[pidx];
        *(unsigned*)&s_u[8192 + (mt * 2 + kb) * 512 + (q * 16 + lm) * 8 + jj] = pk2(v.x, v.y);
    }
    if (t < 64) s_b2[t] = b2[t];
    if (t < 32) {
        s_b3[t] = b3[t];
        s_w4[t] = W4[t];
    }
    const float bias4 = b4[0];
    __syncthreads();

    // ================= per-wave fragment preload =================
    bf16x8_t a2[16];
#pragma unroll
    for (int f = 0; f < 16; ++f) a2[f] = *(const bf16x8_t*)&s_u[f * 512 + lane * 8];
    bf16x8_t a3[4];
#pragma unroll
    for (int f = 0; f < 4; ++f) a3[f] = *(const bf16x8_t*)&s_u[8192 + f * 512 + lane * 8];
    float4 b2q[4];
#pragma unroll
    for (int mt = 0; mt < 4; ++mt) b2q[mt] = *(const float4*)&s_b2[mt * 16 + quad * 4];
    float4 b3q[2];
    f32x2_t w4lo[2], w4hi[2];
#pragma unroll
    for (int mt = 0; mt < 2; ++mt) {
        b3q[mt] = *(const float4*)&s_b3[mt * 16 + quad * 4];
        float4 wq = *(const float4*)&s_w4[mt * 16 + quad * 4];
        w4lo[mt][0] = wq.x; w4lo[mt][1] = wq.y;
        w4hi[mt][0] = wq.z; w4hi[mt][1] = wq.w;
    }
    __syncthreads();  // union handoff: staging -> h2/z scratch

    const int sw = (l15 & 1) * 32;                    // h2 channel swizzle (shorts)
    unsigned short* h2w = &s_u[w * 2 * 1152];         // 2 slots x 16 pts x 72 shorts
    float* zf = (float*)&s_u[9216];                   // [w][pg&7][i][q]
    const f32x2_t zero2 = {0.0f, 0.0f};
    const int outbase = blockIdx.x * 1024 + w * 256;

    // B-phase tail: layer 3 + w4-dot using PRELOADED h2 fragments
    auto bphase = [&](int pg, bf16x8_t b3f0, bf16x8_t b3f1) {
        f32x2_t z2 = zero2;
#pragma unroll
        for (int mt = 0; mt < 2; ++mt) {
            f32x4_t c;
            c[0] = b3q[mt].x; c[1] = b3q[mt].y; c[2] = b3q[mt].z; c[3] = b3q[mt].w;
            c = __builtin_amdgcn_mfma_f32_16x16x32_bf16(a3[mt * 2 + 0], b3f0, c, 0, 0, 0);
            c = __builtin_amdgcn_mfma_f32_16x16x32_bf16(a3[mt * 2 + 1], b3f1, c, 0, 0, 0);
            f32x2_t h01 = __builtin_elementwise_max((f32x2_t){c[0], c[1]}, zero2);
            f32x2_t h23 = __builtin_elementwise_max((f32x2_t){c[2], c[3]}, zero2);
            z2 = __builtin_elementwise_fma(w4lo[mt], h01, z2);
            z2 = __builtin_elementwise_fma(w4hi[mt], h23, z2);
        }
        zf[w * 512 + (pg & 7) * 64 + l15 * 4 + quad] = z2[0] + z2[1];
    };
    // phase C: batched reduce + sigmoid + coalesced store for an 8-ng batch
    auto cphase = [&](int batch) {
#pragma unroll
        for (int half = 0; half < 2; ++half) {
            const int p = lane + 64 * half;   // point within this batch's 128
            const int pg = p >> 4, i = p & 15;
            float4 v = *(const float4*)&zf[w * 512 + pg * 64 + i * 4];
            float z = (v.x + v.y) + (v.z + v.w) + bias4;
            out[outbase + batch * 128 + p] = 1.0f / (1.0f + __expf(-z));
        }
    };

    // ========== pipelined main loop: prefetch b3f(ng-1), A(ng), B(ng-1) ==========
#pragma unroll 2
    for (int ng = 0; ng < 16; ++ng) {
        // ---- prefetch h2 fragments for bphase(ng-1): slot (ng-1)&1 is disjoint
        // from the slot A(ng) writes; same-wave DS completes in order ----
        bf16x8_t b3f0, b3f1;
        if (ng > 0) {
            const unsigned short* pslot = h2w + ((ng - 1) & 1) * 1152 + l15 * 72;
            b3f0 = *(const bf16x8_t*)&pslot[(0 ^ sw) + quad * 8];
            b3f1 = *(const bf16x8_t*)&pslot[(32 ^ sw) + quad * 8];
        }

        const float* dj = &s_base[w * 2 + (ng >> 3)][0];
        const float pc = fmaf(step, (float)(((ng & 7) * 16) + l15), -1.0f);
        const f32x2_t pc2 = {pc, pc};

        // ---- A: h1 into B-fragments via packed fma/max (LDS b128 table reads) ----
        bf16x8_t bfrag[4];
#pragma unroll
        for (int kb = 0; kb < 4; ++kb) {
            union { bf16x8_t v; unsigned u[4]; } bb;
#pragma unroll
            for (int half = 0; half < 2; ++half) {
                const int o = kb * 32 + quad * 8 + half * 4;
                float4 bs = *(const float4*)&dj[o];
                float4 wc4 = *(const float4*)&s_wc[o];
                f32x2_t h01 = __builtin_elementwise_fma(
                    (f32x2_t){wc4.x, wc4.y}, pc2, (f32x2_t){bs.x, bs.y});
                f32x2_t h23 = __builtin_elementwise_fma(
                    (f32x2_t){wc4.z, wc4.w}, pc2, (f32x2_t){bs.z, bs.w});
                h01 = __builtin_elementwise_max(h01, zero2);
                h23 = __builtin_elementwise_max(h23, zero2);
                bb.u[half * 2 + 0] = pk2(h01[0], h01[1]);
                bb.u[half * 2 + 1] = pk2(h23[0], h23[1]);
            }
            bfrag[kb] = bb.v;
        }
        // ---- A: layer 2 MFMA, bias in C-init ----
        f32x4_t acc2[4];
#pragma unroll
        for (int mt = 0; mt < 4; ++mt) {
            f32x4_t c;
            c[0] = b2q[mt].x; c[1] = b2q[mt].y; c[2] = b2q[mt].z; c[3] = b2q[mt].w;
#pragma unroll
            for (int kb = 0; kb < 4; ++kb)
                c = __builtin_amdgcn_mfma_f32_16x16x32_bf16(a2[mt * 4 + kb], bfrag[kb], c, 0, 0, 0);
            acc2[mt] = c;
        }
        // ---- A: packed relu + pack + write h2 slot ng&1 ----
        unsigned short* slot = h2w + (ng & 1) * 1152 + l15 * 72;
#pragma unroll
        for (int mt = 0; mt < 4; ++mt) {
            f32x2_t v01 = __builtin_elementwise_max((f32x2_t){acc2[mt][0], acc2[mt][1]}, zero2);
            f32x2_t v23 = __builtin_elementwise_max((f32x2_t){acc2[mt][2], acc2[mt][3]}, zero2);
            uint2 pk;
            pk.x = pk2(v01[0], v01[1]);
            pk.y = pk2(v23[0], v23[1]);
            *(uint2*)&slot[(mt * 16 + quad * 4) ^ sw] = pk;
        }
        // ---- B for previous group (fragments already in registers) ----
        if (ng > 0) {
            bphase(ng - 1, b3f0, b3f1);
            if (((ng - 1) & 7) == 7) cphase((ng - 1) >> 3);
        }
    }
    {   // drain: bphase(15) with direct reads
        const unsigned short* pslot = h2w + (15 & 1) * 1152 + l15 * 72;
        bf16x8_t b3f0 = *(const bf16x8_t*)&pslot[(0 ^ sw) + quad * 8];
        bf16x8_t b3f1 = *(const bf16x8_t*)&pslot[(32 ^ sw) + quad * 8];
        bphase(15, b3f0, b3f1);
        cphase(1);
    }
}

extern "C" void kernel_launch(void* const* d_in, const int* in_sizes, int n_in,
                              void* d_out, int out_size, void* d_ws, size_t ws_size,
                              hipStream_t stream) {
    mlp_kernel<<<NPTS / 1024, 256, 0, stream>>>(
        (const float*)d_in[0], (const float*)d_in[1], (const float*)d_in[2],
        (const float*)d_in[3], (const float*)d_in[4], (const float*)d_in[5],
        (const float*)d_in[6], (const float*)d_in[7], (const float*)d_in[8],
        (float*)d_out);
}

// Round 16
// 240.541 us; speedup vs baseline: 1.3773x; 1.3773x over previous
//
#include <hip/hip_runtime.h>
#include <hip/hip_bf16.h>

// GeneratorSDF: latent-conditioned MLP SDF on a 128^3 grid (fp32 I/O).
// dims: 67 -> 128 -> 64 -> 32 -> 1 (relu, relu, relu, sigmoid)
//
// R16 = R15 minus 32 registers. R15 forensics: (256,3) budget = 170 total;
// demand was ~196 (116 VGPR + ~80 AGPR: a2=64, a3=16) -> ~30-reg spill,
// FETCH 474MB, 273us. But occupancy DID rise to 29% — residency works, demand
// was just over budget. Fix: b2q/b3q/w4 (32 regs, used once per ng, quad-
// uniform addresses -> 2-way LDS = free per m136) become per-use LDS reads.
// New demand ~164 <= 170 -> (256,3) fits WITHOUT spill.
// Keeps: grid 2048 (1024 pts/block, 16 ng; 8 blocks/CU pipeline through 3
// resident), cheap 3-instr pk2 (R14), pipelined h2 double-buffer + b3f
// prefetch (R8/R12), batched cphase, LDS union.
// MFMA layouts (verified m89/m91): A[m=lane&15][k=quad*8+j],
// B[k=quad*8+j][n=lane&15], C/D row=quad*4+reg, col=lane&15.

#define NPTS (128 * 128 * 128)

typedef float f32x4_t __attribute__((ext_vector_type(4)));
typedef float f32x2_t __attribute__((ext_vector_type(2)));
typedef short bf16x8_t __attribute__((ext_vector_type(8)));

// f32x2 -> packed bf16x2, round-half-up: 2x v_add_u32 + 1x v_perm_b32.
__device__ __forceinline__ unsigned pk2(float lo, float hi) {
    unsigned a, b;
    __builtin_memcpy(&a, &lo, 4);
    __builtin_memcpy(&b, &hi, 4);
    return __builtin_amdgcn_perm(b + 0x8000u, a + 0x8000u, 0x07060302u);
}

__global__ __launch_bounds__(256, 3) void mlp_kernel(
    const float* __restrict__ x,  const float* __restrict__ W1,
    const float* __restrict__ b1, const float* __restrict__ W2,
    const float* __restrict__ b2, const float* __restrict__ W3,
    const float* __restrict__ b3, const float* __restrict__ W4,
    const float* __restrict__ b4, float* __restrict__ out) {
    __shared__ __align__(16) float s_base[8][128];   // j-row: base+wa*pa+wb*pb_j
    __shared__ __align__(16) float s_wc[128];        // wc[k]
    __shared__ __align__(16) float s_b2[64];
    __shared__ __align__(16) float s_b3[32];
    __shared__ __align__(16) float s_w4[32];
    // Union (26.6 KB): staging = w2a[16][64][8] (shorts 0..8191) + w3a[4][64][8]
    // (8192..10239); runtime = h2 slots [w][2][16][72] (0..9215) + z floats
    // (shorts 9216..13311 = float[4][8][16][4] : w*512 + pg*64 + i*4 + q).
    __shared__ __align__(16) unsigned short s_u[13312];

    const int t = threadIdx.x;
    const int w = t >> 6;
    const int lane = t & 63;
    const int quad = lane >> 4;
    const int l15 = lane & 15;
    const float step = 2.0f / 127.0f;

    // ================= per-block prep =================
    if (t < 128) {
        const float* w1row = W1 + t * 67;
        float s = b1[t];
#pragma unroll 8
        for (int c = 0; c < 64; ++c) s = fmaf(w1row[c], x[c], s);
        const float wa = w1row[64], wb = w1row[65], wc = w1row[66];
        const float pa = -1.0f + step * (float)(blockIdx.x >> 4);   // gi
        const float base = fmaf(wa, pa, s);
        const int gj0 = (blockIdx.x & 15) * 8;
        s_wc[t] = wc;
#pragma unroll
        for (int j = 0; j < 8; ++j) {
            const float pb = -1.0f + step * (float)(gj0 + j);
            s_base[j][t] = fmaf(wb, pb, base);
        }
    }
    // W2 [64][128] -> bf16 A-frag staging
    const float2* W2v = (const float2*)W2;
#pragma unroll
    for (int it = 0; it < 16; ++it) {
        int pidx = t + 256 * it;
        int idx2 = pidx * 2;
        int o = idx2 >> 7, k = idx2 & 127;
        int mt = o >> 4, lm = o & 15;
        int kb = k >> 5, q = (k >> 3) & 3, jj = k & 7;
        float2 v = W2v[pidx];
        *(unsigned*)&s_u[(mt * 4 + kb) * 512 + (q * 16 + lm) * 8 + jj] = pk2(v.x, v.y);
    }
    // W3 [32][64] -> bf16 A-frag staging
    const float2* W3v = (const float2*)W3;
#pragma unroll
    for (int it = 0; it < 4; ++it) {
        int pidx = t + 256 * it;
        int idx2 = pidx * 2;
        int o = idx2 >> 6, k = idx2 & 63;
        int mt = o >> 4, lm = o & 15;
        int kb = k >> 5, q = (k >> 3) & 3, jj = k & 7;
        float2 v = W3v[pidx];
        *(unsigned*)&s_u[8192 + (mt * 2 + kb) * 512 + (q * 16 + lm) * 8 + jj] = pk2(v.x, v.y);
    }
    if (t < 64) s_b2[t] = b2[t];
    if (t < 32) {
        s_b3[t] = b3[t];
        s_w4[t] = W4[t];
    }
    const float bias4 = b4[0];
    __syncthreads();

    // ================= per-wave fragment preload (a2/a3 only) =================
    bf16x8_t a2[16];
#pragma unroll
    for (int f = 0; f < 16; ++f) a2[f] = *(const bf16x8_t*)&s_u[f * 512 + lane * 8];
    bf16x8_t a3[4];
#pragma unroll
    for (int f = 0; f < 4; ++f) a3[f] = *(const bf16x8_t*)&s_u[8192 + f * 512 + lane * 8];
    __syncthreads();  // union handoff: staging -> h2/z scratch

    const int sw = (l15 & 1) * 32;                    // h2 channel swizzle (shorts)
    unsigned short* h2w = &s_u[w * 2 * 1152];         // 2 slots x 16 pts x 72 shorts
    float* zf = (float*)&s_u[9216];                   // [w][pg&7][i][q]
    const f32x2_t zero2 = {0.0f, 0.0f};
    const int outbase = blockIdx.x * 1024 + w * 256;

    // B-phase tail: layer 3 + w4-dot; biases/w4 read per-use from LDS
    // (quad-uniform b128 -> 2-way banked, free).
    auto bphase = [&](int pg, bf16x8_t b3f0, bf16x8_t b3f1) {
        f32x2_t z2 = zero2;
#pragma unroll
        for (int mt = 0; mt < 2; ++mt) {
            f32x4_t c = *(const f32x4_t*)&s_b3[mt * 16 + quad * 4];
            c = __builtin_amdgcn_mfma_f32_16x16x32_bf16(a3[mt * 2 + 0], b3f0, c, 0, 0, 0);
            c = __builtin_amdgcn_mfma_f32_16x16x32_bf16(a3[mt * 2 + 1], b3f1, c, 0, 0, 0);
            float4 wq = *(const float4*)&s_w4[mt * 16 + quad * 4];
            f32x2_t h01 = __builtin_elementwise_max((f32x2_t){c[0], c[1]}, zero2);
            f32x2_t h23 = __builtin_elementwise_max((f32x2_t){c[2], c[3]}, zero2);
            z2 = __builtin_elementwise_fma((f32x2_t){wq.x, wq.y}, h01, z2);
            z2 = __builtin_elementwise_fma((f32x2_t){wq.z, wq.w}, h23, z2);
        }
        zf[w * 512 + (pg & 7) * 64 + l15 * 4 + quad] = z2[0] + z2[1];
    };
    // phase C: batched reduce + sigmoid + coalesced store for an 8-ng batch
    auto cphase = [&](int batch) {
#pragma unroll
        for (int half = 0; half < 2; ++half) {
            const int p = lane + 64 * half;   // point within this batch's 128
            const int pg = p >> 4, i = p & 15;
            float4 v = *(const float4*)&zf[w * 512 + pg * 64 + i * 4];
            float z = (v.x + v.y) + (v.z + v.w) + bias4;
            out[outbase + batch * 128 + p] = 1.0f / (1.0f + __expf(-z));
        }
    };

    // ========== pipelined main loop: prefetch b3f(ng-1), A(ng), B(ng-1) ==========
#pragma unroll 2
    for (int ng = 0; ng < 16; ++ng) {
        // ---- prefetch h2 fragments for bphase(ng-1): slot (ng-1)&1 is disjoint
        // from the slot A(ng) writes; same-wave DS completes in order ----
        bf16x8_t b3f0, b3f1;
        if (ng > 0) {
            const unsigned short* pslot = h2w + ((ng - 1) & 1) * 1152 + l15 * 72;
            b3f0 = *(const bf16x8_t*)&pslot[(0 ^ sw) + quad * 8];
            b3f1 = *(const bf16x8_t*)&pslot[(32 ^ sw) + quad * 8];
        }

        const float* dj = &s_base[w * 2 + (ng >> 3)][0];
        const float pc = fmaf(step, (float)(((ng & 7) * 16) + l15), -1.0f);
        const f32x2_t pc2 = {pc, pc};

        // ---- A: h1 into B-fragments via packed fma/max (LDS b128 table reads) ----
        bf16x8_t bfrag[4];
#pragma unroll
        for (int kb = 0; kb < 4; ++kb) {
            union { bf16x8_t v; unsigned u[4]; } bb;
#pragma unroll
            for (int half = 0; half < 2; ++half) {
                const int o = kb * 32 + quad * 8 + half * 4;
                float4 bs = *(const float4*)&dj[o];
                float4 wc4 = *(const float4*)&s_wc[o];
                f32x2_t h01 = __builtin_elementwise_fma(
                    (f32x2_t){wc4.x, wc4.y}, pc2, (f32x2_t){bs.x, bs.y});
                f32x2_t h23 = __builtin_elementwise_fma(
                    (f32x2_t){wc4.z, wc4.w}, pc2, (f32x2_t){bs.z, bs.w});
                h01 = __builtin_elementwise_max(h01, zero2);
                h23 = __builtin_elementwise_max(h23, zero2);
                bb.u[half * 2 + 0] = pk2(h01[0], h01[1]);
                bb.u[half * 2 + 1] = pk2(h23[0], h23[1]);
            }
            bfrag[kb] = bb.v;
        }
        // ---- A: layer 2 MFMA, bias C-init read per-mt from LDS ----
        f32x4_t acc2[4];
#pragma unroll
        for (int mt = 0; mt < 4; ++mt) {
            f32x4_t c = *(const f32x4_t*)&s_b2[mt * 16 + quad * 4];
#pragma unroll
            for (int kb = 0; kb < 4; ++kb)
                c = __builtin_amdgcn_mfma_f32_16x16x32_bf16(a2[mt * 4 + kb], bfrag[kb], c, 0, 0, 0);
            acc2[mt] = c;
        }
        // ---- A: packed relu + pack + write h2 slot ng&1 ----
        unsigned short* slot = h2w + (ng & 1) * 1152 + l15 * 72;
#pragma unroll
        for (int mt = 0; mt < 4; ++mt) {
            f32x2_t v01 = __builtin_elementwise_max((f32x2_t){acc2[mt][0], acc2[mt][1]}, zero2);
            f32x2_t v23 = __builtin_elementwise_max((f32x2_t){acc2[mt][2], acc2[mt][3]}, zero2);
            uint2 pk;
            pk.x = pk2(v01[0], v01[1]);
            pk.y = pk2(v23[0], v23[1]);
            *(uint2*)&slot[(mt * 16 + quad * 4) ^ sw] = pk;
        }
        // ---- B for previous group (fragments already in registers) ----
        if (ng > 0) {
            bphase(ng - 1, b3f0, b3f1);
            if (((ng - 1) & 7) == 7) cphase((ng - 1) >> 3);
        }
    }
    {   // drain: bphase(15) with direct reads
        const unsigned short* pslot = h2w + (15 & 1) * 1152 + l15 * 72;
        bf16x8_t b3f0 = *(const bf16x8_t*)&pslot[(0 ^ sw) + quad * 8];
        bf16x8_t b3f1 = *(const bf16x8_t*)&pslot[(32 ^ sw) + quad * 8];
        bphase(15, b3f0, b3f1);
        cphase(1);
    }
}

extern "C" void kernel_launch(void* const* d_in, const int* in_sizes, int n_in,
                              void* d_out, int out_size, void* d_ws, size_t ws_size,
                              hipStream_t stream) {
    mlp_kernel<<<NPTS / 1024, 256, 0, stream>>>(
        (const float*)d_in[0], (const float*)d_in[1], (const float*)d_in[2],
        (const float*)d_in[3], (const float*)d_in[4], (const float*)d_in[5],
        (const float*)d_in[6], (const float*)d_in[7], (const float*)d_in[8],
        (float*)d_out);
}

// Round 18
// 115.358 us; speedup vs baseline: 2.8719x; 2.0852x over previous
//
#include <hip/hip_runtime.h>
#include <hip/hip_bf16.h>
#include <hip/hip_fp16.h>

// GeneratorSDF: latent-conditioned MLP SDF on a 128^3 grid (fp32 I/O).
// dims: 67 -> 128 -> 64 -> 32 -> 1 (relu, relu, relu, sigmoid)
//
// R18 = R17 with the type fix: __builtin_amdgcn_cvt_pkrtz returns a
// __fp16-element vector, not _Float16. VALU half2 math uses g16x2_t (__fp16);
// MFMA fragments use h16x8_t (_Float16, matching the mfma builtin); they
// exchange bytes via unions/memcpy (identical layout).
// R17 theory (from R14 forensics): ~425 VALU instr/wave-ng, dominated by fp32
// h1-build + manual bf16 packs that exist only because MFMA needs 16-bit in.
// fp16 datapath: v_pk_fma_f16 / v_pk_max_f16 (1 instr/pair),
// v_cvt_pkrtz_f16_f32 (1 instr/2 cvts), mfma_f32_16x16x32_f16 (same
// rate/layout; C/D layout dtype-independent m121-128). Accuracy improves
// (10-bit mantissa, values O(10) — no overflow).
// Structure: grid 1024 (2048 pts/block, jrow-outer 4x8 ng), pipelined h2
// double-buffer + b3f prefetch, batched cphase, LDS union, (256,2)
// (R15/R16: residency-3 bounds always spill — demand ~196 > 170).
// MFMA layouts (verified m89/m91): A[m=lane&15][k=quad*8+j],
// B[k=quad*8+j][n=lane&15], C/D row=quad*4+reg, col=lane&15.

#define NPTS (128 * 128 * 128)

typedef float f32x4_t __attribute__((ext_vector_type(4)));
typedef float f32x2_t __attribute__((ext_vector_type(2)));
typedef __fp16 g16x2_t __attribute__((ext_vector_type(2)));    // VALU half2 (cvt_pkrtz type)
typedef _Float16 h16x8_t __attribute__((ext_vector_type(8)));  // MFMA fragment

__device__ __forceinline__ unsigned h2u(g16x2_t h) {
    unsigned u;
    __builtin_memcpy(&u, &h, 4);
    return u;
}
__device__ __forceinline__ g16x2_t u2h(unsigned u) {
    g16x2_t h;
    __builtin_memcpy(&h, &u, 4);
    return h;
}

__global__ __launch_bounds__(256, 2) void mlp_kernel(
    const float* __restrict__ x,  const float* __restrict__ W1,
    const float* __restrict__ b1, const float* __restrict__ W2,
    const float* __restrict__ b2, const float* __restrict__ W3,
    const float* __restrict__ b3, const float* __restrict__ W4,
    const float* __restrict__ b4, float* __restrict__ out) {
    __shared__ __align__(16) unsigned s_basep[16][64];  // half2 {base[2c],base[2c+1]} per j
    __shared__ __align__(16) unsigned s_wcp[64];        // half2 wc pairs
    __shared__ __align__(16) float s_b2[64];
    __shared__ __align__(16) float s_b3[32];
    __shared__ __align__(16) float s_w4[32];
    // Union (26.6 KB): staging = w2a[16][64][8] halves (0..8191) + w3a[4][64][8]
    // (8192..10239); runtime = h2 slots [w][2][16][72] (0..9215) + z floats
    // (shorts 9216..13311 = float[4][8][16][4] : w*512 + pg*64 + i*4 + q).
    __shared__ __align__(16) unsigned short s_u[13312];

    const int t = threadIdx.x;
    const int w = t >> 6;
    const int lane = t & 63;
    const int quad = lane >> 4;
    const int l15 = lane & 15;
    const float step = 2.0f / 127.0f;

    // ================= per-block prep =================
    // Thread t<64 handles channel pair (2t, 2t+1): fold latent + pa + all 16 pb.
    if (t < 64) {
        const float* r0 = W1 + (2 * t) * 67;
        const float* r1 = r0 + 67;
        float s0 = b1[2 * t], s1 = b1[2 * t + 1];
#pragma unroll 8
        for (int c = 0; c < 64; ++c) {
            const float xc = x[c];
            s0 = fmaf(r0[c], xc, s0);
            s1 = fmaf(r1[c], xc, s1);
        }
        const float pa = -1.0f + step * (float)(blockIdx.x >> 3);   // gi
        const float base0 = fmaf(r0[64], pa, s0);
        const float base1 = fmaf(r1[64], pa, s1);
        const float wb0 = r0[65], wb1 = r1[65];
        const int gj0 = (blockIdx.x & 7) * 16;
        s_wcp[t] = h2u(__builtin_amdgcn_cvt_pkrtz(r0[66], r1[66]));
#pragma unroll
        for (int j = 0; j < 16; ++j) {
            const float pb = -1.0f + step * (float)(gj0 + j);
            s_basep[j][t] = h2u(__builtin_amdgcn_cvt_pkrtz(
                fmaf(wb0, pb, base0), fmaf(wb1, pb, base1)));
        }
    }
    // W2 [64][128] -> f16 A-frag staging (pairs along k)
    const float2* W2v = (const float2*)W2;
#pragma unroll
    for (int it = 0; it < 16; ++it) {
        int pidx = t + 256 * it;
        int idx2 = pidx * 2;
        int o = idx2 >> 7, k = idx2 & 127;
        int mt = o >> 4, lm = o & 15;
        int kb = k >> 5, q = (k >> 3) & 3, jj = k & 7;
        float2 v = W2v[pidx];
        *(unsigned*)&s_u[(mt * 4 + kb) * 512 + (q * 16 + lm) * 8 + jj] =
            h2u(__builtin_amdgcn_cvt_pkrtz(v.x, v.y));
    }
    // W3 [32][64] -> f16 A-frag staging
    const float2* W3v = (const float2*)W3;
#pragma unroll
    for (int it = 0; it < 4; ++it) {
        int pidx = t + 256 * it;
        int idx2 = pidx * 2;
        int o = idx2 >> 6, k = idx2 & 63;
        int mt = o >> 4, lm = o & 15;
        int kb = k >> 5, q = (k >> 3) & 3, jj = k & 7;
        float2 v = W3v[pidx];
        *(unsigned*)&s_u[8192 + (mt * 2 + kb) * 512 + (q * 16 + lm) * 8 + jj] =
            h2u(__builtin_amdgcn_cvt_pkrtz(v.x, v.y));
    }
    if (t < 64) s_b2[t] = b2[t];
    if (t < 32) {
        s_b3[t] = b3[t];
        s_w4[t] = W4[t];
    }
    const float bias4 = b4[0];
    __syncthreads();

    // ================= per-wave fragment preload =================
    h16x8_t a2[16];
#pragma unroll
    for (int f = 0; f < 16; ++f) a2[f] = *(const h16x8_t*)&s_u[f * 512 + lane * 8];
    h16x8_t a3[4];
#pragma unroll
    for (int f = 0; f < 4; ++f) a3[f] = *(const h16x8_t*)&s_u[8192 + f * 512 + lane * 8];
    f32x4_t b2q[4];
#pragma unroll
    for (int mt = 0; mt < 4; ++mt) b2q[mt] = *(const f32x4_t*)&s_b2[mt * 16 + quad * 4];
    f32x4_t b3q[2];
    f32x2_t w4lo[2], w4hi[2];
#pragma unroll
    for (int mt = 0; mt < 2; ++mt) {
        b3q[mt] = *(const f32x4_t*)&s_b3[mt * 16 + quad * 4];
        float4 wq = *(const float4*)&s_w4[mt * 16 + quad * 4];
        w4lo[mt][0] = wq.x; w4lo[mt][1] = wq.y;
        w4hi[mt][0] = wq.z; w4hi[mt][1] = wq.w;
    }
    // wc pairs: loop-invariant, 16 packed regs, pinned
    unsigned twp[16];
#pragma unroll
    for (int kb = 0; kb < 4; ++kb) {
        uint4 v = *(const uint4*)&s_wcp[kb * 16 + quad * 4];
        twp[kb * 4 + 0] = v.x; twp[kb * 4 + 1] = v.y;
        twp[kb * 4 + 2] = v.z; twp[kb * 4 + 3] = v.w;
    }
#pragma unroll
    for (int i = 0; i < 16; ++i) asm volatile("" : "+v"(twp[i]));
    __syncthreads();  // union handoff: staging -> h2/z scratch

    const int sw = (l15 & 1) * 32;                    // h2 channel swizzle (shorts)
    unsigned short* h2w = &s_u[w * 2 * 1152];         // 2 slots x 16 pts x 72 shorts
    float* zf = (float*)&s_u[9216];                   // [w][pg&7][i][q]
    const f32x2_t zero2 = {0.0f, 0.0f};
    const g16x2_t zero2h = {(__fp16)0.0f, (__fp16)0.0f};
    const int outbase = blockIdx.x * 2048 + w * 512;

    // B-phase tail: layer 3 + w4-dot using PRELOADED h2 fragments
    auto bphase = [&](int pg, h16x8_t b3f0, h16x8_t b3f1) {
        f32x2_t z2 = zero2;
#pragma unroll
        for (int mt = 0; mt < 2; ++mt) {
            f32x4_t c = b3q[mt];
            c = __builtin_amdgcn_mfma_f32_16x16x32_f16(a3[mt * 2 + 0], b3f0, c, 0, 0, 0);
            c = __builtin_amdgcn_mfma_f32_16x16x32_f16(a3[mt * 2 + 1], b3f1, c, 0, 0, 0);
            f32x2_t h01 = __builtin_elementwise_max((f32x2_t){c[0], c[1]}, zero2);
            f32x2_t h23 = __builtin_elementwise_max((f32x2_t){c[2], c[3]}, zero2);
            z2 = __builtin_elementwise_fma(w4lo[mt], h01, z2);
            z2 = __builtin_elementwise_fma(w4hi[mt], h23, z2);
        }
        zf[w * 512 + (pg & 7) * 64 + l15 * 4 + quad] = z2[0] + z2[1];
    };
    // phase C: batched reduce + sigmoid + coalesced store for an 8-ng batch
    auto cphase = [&](int batch) {
#pragma unroll
        for (int half = 0; half < 2; ++half) {
            const int p = lane + 64 * half;   // point within this batch's 128
            const int pg = p >> 4, i = p & 15;
            float4 v = *(const float4*)&zf[w * 512 + pg * 64 + i * 4];
            float z = (v.x + v.y) + (v.z + v.w) + bias4;
            out[outbase + batch * 128 + p] = 1.0f / (1.0f + __expf(-z));
        }
    };

    // ========== jrow-outer main loop ==========
    for (int jrow = 0; jrow < 4; ++jrow) {
        // base pairs for this jrow: 16 packed regs, pinned
        const unsigned* bp = &s_basep[w * 4 + jrow][0];
        unsigned tbp[16];
#pragma unroll
        for (int kb = 0; kb < 4; ++kb) {
            uint4 v = *(const uint4*)&bp[kb * 16 + quad * 4];
            tbp[kb * 4 + 0] = v.x; tbp[kb * 4 + 1] = v.y;
            tbp[kb * 4 + 2] = v.z; tbp[kb * 4 + 3] = v.w;
        }
#pragma unroll
        for (int i = 0; i < 16; ++i) asm volatile("" : "+v"(tbp[i]));

#pragma unroll 2
        for (int pg = 0; pg < 8; ++pg) {
            const int ng = jrow * 8 + pg;
            // ---- prefetch h2 fragments for bphase(ng-1) ----
            h16x8_t b3f0, b3f1;
            if (ng > 0) {
                const unsigned short* pslot = h2w + ((ng - 1) & 1) * 1152 + l15 * 72;
                b3f0 = *(const h16x8_t*)&pslot[(0 ^ sw) + quad * 8];
                b3f1 = *(const h16x8_t*)&pslot[(32 ^ sw) + quad * 8];
            }

            const float pc = fmaf(step, (float)((pg * 16) + l15), -1.0f);
            const g16x2_t pc2 = __builtin_amdgcn_cvt_pkrtz(pc, pc);

            // ---- A: h1 via packed f16 fma/max, straight into B-fragments ----
            h16x8_t bfrag[4];
#pragma unroll
            for (int kb = 0; kb < 4; ++kb) {
                union { h16x8_t v; g16x2_t h[4]; } bb;
#pragma unroll
                for (int p = 0; p < 4; ++p) {
                    g16x2_t hh = __builtin_elementwise_fma(
                        u2h(twp[kb * 4 + p]), pc2, u2h(tbp[kb * 4 + p]));
                    bb.h[p] = __builtin_elementwise_max(hh, zero2h);
                }
                bfrag[kb] = bb.v;
            }
            // ---- A: layer 2 MFMA (f16), bias in C-init ----
            f32x4_t acc2[4];
#pragma unroll
            for (int mt = 0; mt < 4; ++mt) {
                f32x4_t c = b2q[mt];
#pragma unroll
                for (int kb = 0; kb < 4; ++kb)
                    c = __builtin_amdgcn_mfma_f32_16x16x32_f16(a2[mt * 4 + kb], bfrag[kb], c, 0, 0, 0);
                acc2[mt] = c;
            }
            // ---- A: pack (cvt_pkrtz) + relu (pk_max_f16) + write h2 slot ----
            unsigned short* slot = h2w + (ng & 1) * 1152 + l15 * 72;
#pragma unroll
            for (int mt = 0; mt < 4; ++mt) {
                g16x2_t lo = __builtin_elementwise_max(
                    __builtin_amdgcn_cvt_pkrtz(acc2[mt][0], acc2[mt][1]), zero2h);
                g16x2_t hi = __builtin_elementwise_max(
                    __builtin_amdgcn_cvt_pkrtz(acc2[mt][2], acc2[mt][3]), zero2h);
                uint2 pk;
                pk.x = h2u(lo);
                pk.y = h2u(hi);
                *(uint2*)&slot[(mt * 16 + quad * 4) ^ sw] = pk;
            }
            // ---- B for previous group (fragments already in registers) ----
            if (ng > 0) {
                bphase(ng - 1, b3f0, b3f1);
                if (((ng - 1) & 7) == 7) cphase((ng - 1) >> 3);
            }
        }
    }
    {   // drain: bphase(31) with direct reads
        const unsigned short* pslot = h2w + (31 & 1) * 1152 + l15 * 72;
        h16x8_t b3f0 = *(const h16x8_t*)&pslot[(0 ^ sw) + quad * 8];
        h16x8_t b3f1 = *(const h16x8_t*)&pslot[(32 ^ sw) + quad * 8];
        bphase(31, b3f0, b3f1);
        cphase(3);
    }
}

extern "C" void kernel_launch(void* const* d_in, const int* in_sizes, int n_in,
                              void* d_out, int out_size, void* d_ws, size_t ws_size,
                              hipStream_t stream) {
    mlp_kernel<<<NPTS / 2048, 256, 0, stream>>>(
        (const float*)d_in[0], (const float*)d_in[1], (const float*)d_in[2],
        (const float*)d_in[3], (const float*)d_in[4], (const float*)d_in[5],
        (const float*)d_in[6], (const float*)d_in[7], (const float*)d_in[8],
        (float*)d_out);
}